// Round 11
// baseline (17303.777 us; speedup 1.0000x reference)
//
#include <hip/hip_runtime.h>
#include <hip/hip_bf16.h>
#include <math.h>

typedef unsigned long long u64;
typedef unsigned int u32;

#define T_STEPS 8192
#define HDIM    512
#define NBLK_HW 256          // launched blocks; members are b%8==0 (XCD 0)
#define SPIN_MAX (1 << 20)   // device-path spin bound
#define LSPIN    2048        // local-path spin budget before sticky fallback
#define WARM     8           // device-path warmup steps

#if __has_builtin(__builtin_amdgcn_rcpf)
#define DEV_RCP(x) __builtin_amdgcn_rcpf(x)
#else
#define DEV_RCP(x) (1.0f / (x))
#endif
#if __has_builtin(__builtin_amdgcn_exp2f)
#define DEV_EXP2(x) __builtin_amdgcn_exp2f(x)
#else
#define DEV_EXP2(x) exp2f(x)
#endif

__device__ __forceinline__ float fast_sigmoid(float x) {
    float e = DEV_EXP2(-1.4426950408889634f * x);
    return DEV_RCP(1.0f + e);
}
__device__ __forceinline__ float fast_tanh(float x) {
    x = fminf(20.0f, fmaxf(-20.0f, x));
    float e = DEV_EXP2(-2.8853900817779268f * x);  // e^{-2x}
    return (1.0f - e) * DEV_RCP(1.0f + e);
}

// r22 = r21 + the ONE-variable fix: __launch_bounds__(1024, 4).
// r21 post-mortem: design PASSED (absmax 0) but VGPR_Count=56 -> with
// __launch_bounds__(1024, 1) the allocator targeted 2 blocks/CU (32
// waves/CU -> 64-VGPR cap), so W=64 floats spilled to scratch (FETCH
// 42->52MB, occupancy 2x). launch_bounds semantics (guide §1): for
// B=1024 = 16 waves/block, w waves/EU -> k = w*4/16 blocks/CU; w=4 ->
// k=1 block/CU, VGPR cap 512/4 = 128. W(64)+accs+poll state ~100 fits.
//
// Structure (verified correct in r21): wave he (0..15) owns h-element
// b*16+he's 4 gate rows; lane covers k in {4*lane+j, 256+4*lane+j} ->
// 4 lane-consecutive ds_read_b128/thread/step (64KB/step vs r17's 256KB).
// Reduce: r20-verified DPP ladder (32-groups) + shfl_xor(32); lane16
// holds full 64-sums -> bias + activation -> gate_lds[g*16+he].
// Publisher split: wave0 tid<16 -> hpL (L2) + out; wave8 tid 512-527
// replicates E deterministically and stores hpD (MALL) -- wave8 never
// polls, so no vmcnt(0) ever drains its store. Consumer protocol
// verbatim r19: per-thread exact-tag parity dbuf, sc0 local poll,
// sticky local->device fallback, SPIN_MAX + sdead sentinel.
// Hazards (r21-verified): x_lds W(D,t) vs R(B,t): B-reads retired at own
// lgkmcnt at #1(t); vs R(B,t+1): #2(t). h_lds W(C,t) vs R(D,t): #1(t);
// R(D,t) vs W(C,t+1): #2(t). gate_lds W(D,t) vs R(E/E',t): #2(t);
// R(E/E',t) vs W(D,t+1): #1(t+1). Packet WAR: r9 transitive argument.

__global__ void probe_gate_r22(const float* __restrict__ wih,
                               const float* __restrict__ x, u32* flag) {
    const int lane = threadIdx.x & 63;
    const u32 wi = ((u32)lane * 16381u) & (1048576u - 1u);
    const u32 xi = ((u32)lane * 65521u) % 4194304u;
    const float wv = wih[wi];
    const float xv = x[xi];
    const bool wok  = (fabsf(wv) <= 0.04425f);            // NaN -> false
    const bool xbig = (fabsf(xv) > 0.5f) && (fabsf(xv) < 100.0f);
    const u64 wm = __ballot(wok);
    const u64 xm = __ballot(xbig);
    if (lane == 0) {
        u32 f = 1u;
        if (__popcll(wm) < 64) f = 2u;
        else if (__popcll(xm) < 8) f = 3u;
        __hip_atomic_store(flag, f, __ATOMIC_RELAXED, __HIP_MEMORY_SCOPE_AGENT);
    }
}

__global__ void diag_sizes_r22(float v, float* out) {
    const int tid = threadIdx.x;
    out[tid] = (tid == 0) ? v : 0.0f;
}

// sc0 load: bypass L1, served by the (XCD-shared) L2. 8B single transaction.
__device__ __forceinline__ u64 load_b64_sc0(const u64* p) {
    u64 r;
    asm volatile("global_load_dwordx2 %0, %1, off sc0\n\t"
                 "s_waitcnt vmcnt(0)"
                 : "=v"(r) : "v"(p) : "memory");
    return r;
}
// plain store: lands in this XCD's L2.
__device__ __forceinline__ void store_b64_l2(u64* p, u64 v) {
    asm volatile("global_store_dwordx2 %0, %1, off"
                 :: "v"(p), "v"(v) : "memory");
}

// LDS-only barrier: drains DS ops, leaves VMEM in flight (no vmcnt drain).
__device__ __forceinline__ void bar_lds() {
    __builtin_amdgcn_sched_barrier(0);
    asm volatile("s_waitcnt lgkmcnt(0)" ::: "memory");
    __builtin_amdgcn_s_barrier();
    __builtin_amdgcn_sched_barrier(0);
}

// DPP add: a += dpp_perm(a). VALU-pipe cross-lane (no DS ops).
#define DPPADD(a, ctrl, rmask)                                              \
    a += __uint_as_float((u32)__builtin_amdgcn_update_dpp(                  \
            0, (int)__float_as_uint(a), (ctrl), (rmask), 0xF, true))
#define DPP_XOR1   0xB1   // quad_perm [1,0,3,2]
#define DPP_XOR2   0x4E   // quad_perm [2,3,0,1]
#define DPP_HMIRR  0x141  // row_half_mirror
#define DPP_MIRR   0x140  // row_mirror
#define DPP_BC15   0x142  // row_bcast15 (row_mask 0xA)

// 32-lane-group sum of 4 accs; sums valid in lanes 16-31 / 48-63.
// (verified r20/r21, absmax 0)
__device__ __forceinline__ void dpp_reduce4(float& a0, float& a1,
                                            float& a2, float& a3) {
    DPPADD(a0, DPP_XOR1, 0xF);  DPPADD(a1, DPP_XOR1, 0xF);
    DPPADD(a2, DPP_XOR1, 0xF);  DPPADD(a3, DPP_XOR1, 0xF);
    DPPADD(a0, DPP_XOR2, 0xF);  DPPADD(a1, DPP_XOR2, 0xF);
    DPPADD(a2, DPP_XOR2, 0xF);  DPPADD(a3, DPP_XOR2, 0xF);
    DPPADD(a0, DPP_HMIRR, 0xF); DPPADD(a1, DPP_HMIRR, 0xF);
    DPPADD(a2, DPP_HMIRR, 0xF); DPPADD(a3, DPP_HMIRR, 0xF);
    DPPADD(a0, DPP_MIRR, 0xF);  DPPADD(a1, DPP_MIRR, 0xF);
    DPPADD(a2, DPP_MIRR, 0xF);  DPPADD(a3, DPP_MIRR, 0xF);
    DPPADD(a0, DPP_BC15, 0xA);  DPPADD(a1, DPP_BC15, 0xA);
    DPPADD(a2, DPP_BC15, 0xA);  DPPADD(a3, DPP_BC15, 0xA);
}

// ---------------------------------------------------------------------------
// Fused persistent LSTM. 256 blocks x 1024 threads (16 waves, 1 block/CU
// enforced via launch_bounds); members b%8==0 (32, one XCD). Member b owns
// h[16b..16b+16). Wave he (0..15) owns h-element b*16+he's 4 gate rows;
// lane covers k in {4*lane+j, 256+4*lane+j}. W = Wx[32]+Wh[32] in VGPRs.
// step = B x-dot (2 b128, 32 FMA) | C tid<512: consume -> h_lds; post-C:
// prefetch x/lk(t+1) | #1 | D h-dot (2 b128, 32 FMA) + DPP/shfl reduce +
// lane16 act -> gate_lds; tid<512 stage x_lds(t+1) | #2 | E wave0: update,
// hpL publish, out || E' wave8: replicated update, hpD publish.
// ---------------------------------------------------------------------------
__global__ __launch_bounds__(1024, 4) void lstm_rec_r22(
        const float* __restrict__ x, const float* __restrict__ likes,
        const float* __restrict__ wih, const float* __restrict__ whh,
        const float* __restrict__ bih, const float* __restrict__ bhh,
        const u32* __restrict__ dflag, u64* hp, float* __restrict__ out) {
    const int tid = threadIdx.x;
    const int bhw = blockIdx.x;
    if (bhw & 7) return;            // non-members exit (other XCDs)
    const int b = bhw >> 3;

    const u32 f = __hip_atomic_load(dflag, __ATOMIC_RELAXED,
                                    __HIP_MEMORY_SCOPE_AGENT);
    if (f != 1u) {
        if (b == 0 && tid == 0) out[0] = (f == 2u) ? 9000.0f : 9500.0f;
        return;
    }

    const int lane = tid & 63;
    const int he   = tid >> 6;          // wave id = h element 0..15
    const bool epub = (tid < 16);               // wave0: hpL + out
    const bool dpub = (tid >= 512 && tid < 528); // wave8: hpD (never polls)
    const int  i16  = tid & 15;                  // publisher h-element

    __shared__ __align__(16) float x_lds[HDIM];
    __shared__ __align__(16) float h_lds[HDIM];
    __shared__ float gate_lds[64];      // ACTIVATED gates: i,f,g,o x 16
    __shared__ int   sdead;

    u64* hpD = hp;                  // device-coherent packet dbuf (MALL path)
    u64* hpL = hp + 2 * HDIM;       // XCD-L2 packet dbuf (fast path)

    // W fragments: Wm[g*8+j]   = m[(g*512+b*16+he)*512 + 4*lane + j]
    //              Wm[g*8+4+j] = m[... + 256 + 4*lane + j]
    float Wx[32], Wh[32];
#pragma unroll
    for (int g = 0; g < 4; ++g) {
        const float* wrx = wih + (size_t)((g << 9) + b * 16 + he) * 512;
        const float* wrh = whh + (size_t)((g << 9) + b * 16 + he) * 512;
        const float4 xa = *(const float4*)(wrx + (lane << 2));
        const float4 xb = *(const float4*)(wrx + 256 + (lane << 2));
        const float4 ha = *(const float4*)(wrh + (lane << 2));
        const float4 hb = *(const float4*)(wrh + 256 + (lane << 2));
        Wx[(g << 3) + 0] = xa.x; Wx[(g << 3) + 1] = xa.y;
        Wx[(g << 3) + 2] = xa.z; Wx[(g << 3) + 3] = xa.w;
        Wx[(g << 3) + 4] = xb.x; Wx[(g << 3) + 5] = xb.y;
        Wx[(g << 3) + 6] = xb.z; Wx[(g << 3) + 7] = xb.w;
        Wh[(g << 3) + 0] = ha.x; Wh[(g << 3) + 1] = ha.y;
        Wh[(g << 3) + 2] = ha.z; Wh[(g << 3) + 3] = ha.w;
        Wh[(g << 3) + 4] = hb.x; Wh[(g << 3) + 5] = hb.y;
        Wh[(g << 3) + 6] = hb.z; Wh[(g << 3) + 7] = hb.w;
    }
    const float bs0 = bih[b * 16 + he]        + bhh[b * 16 + he];
    const float bs1 = bih[512 + b * 16 + he]  + bhh[512 + b * 16 + he];
    const float bs2 = bih[1024 + b * 16 + he] + bhh[1024 + b * 16 + he];
    const float bs3 = bih[1536 + b * 16 + he] + bhh[1536 + b * 16 + he];

    // prologue: stage x[0]; lkc for t=0 (both publisher waves); zero sdead.
    float lkc = 0.0f, lkn = 0.0f;
    if (epub || dpub) lkc = likes[b * 16 + i16];
    if (tid == 0) sdead = 0;
    if (tid < HDIM) x_lds[tid] = x[tid];
    __syncthreads();   // prologue barrier (full): x_lds(0) + sdead visible

    float xr       = 0.0f;   // x[t+1][tid], issued post-C(t)
    float creg     = 0.0f;   // replicated in wave0 and wave8 publisher lanes
    int   dead     = 0;
    int   fellback = 0;      // sticky: local path timed out -> device path

    for (int t = 0; t < T_STEPS; ++t) {
        // ---- B: x-dot (2 lane-consecutive b128 + 32 FMA).
        float a0 = 0.0f, a1 = 0.0f, a2 = 0.0f, a3 = 0.0f;
        {
            const float4* x4 = (const float4*)x_lds;
            const float4 v0 = x4[lane];
            const float4 v1 = x4[64 + lane];
            a0 = fmaf(Wx[0], v0.x, a0); a0 = fmaf(Wx[1], v0.y, a0);
            a0 = fmaf(Wx[2], v0.z, a0); a0 = fmaf(Wx[3], v0.w, a0);
            a0 = fmaf(Wx[4], v1.x, a0); a0 = fmaf(Wx[5], v1.y, a0);
            a0 = fmaf(Wx[6], v1.z, a0); a0 = fmaf(Wx[7], v1.w, a0);
            a1 = fmaf(Wx[8], v0.x, a1); a1 = fmaf(Wx[9], v0.y, a1);
            a1 = fmaf(Wx[10], v0.z, a1); a1 = fmaf(Wx[11], v0.w, a1);
            a1 = fmaf(Wx[12], v1.x, a1); a1 = fmaf(Wx[13], v1.y, a1);
            a1 = fmaf(Wx[14], v1.z, a1); a1 = fmaf(Wx[15], v1.w, a1);
            a2 = fmaf(Wx[16], v0.x, a2); a2 = fmaf(Wx[17], v0.y, a2);
            a2 = fmaf(Wx[18], v0.z, a2); a2 = fmaf(Wx[19], v0.w, a2);
            a2 = fmaf(Wx[20], v1.x, a2); a2 = fmaf(Wx[21], v1.y, a2);
            a2 = fmaf(Wx[22], v1.z, a2); a2 = fmaf(Wx[23], v1.w, a2);
            a3 = fmaf(Wx[24], v0.x, a3); a3 = fmaf(Wx[25], v0.y, a3);
            a3 = fmaf(Wx[26], v0.z, a3); a3 = fmaf(Wx[27], v0.w, a3);
            a3 = fmaf(Wx[28], v1.x, a3); a3 = fmaf(Wx[29], v1.y, a3);
            a3 = fmaf(Wx[30], v1.z, a3); a3 = fmaf(Wx[31], v1.w, a3);
        }

        // ---- C: tid<512 obtain h_t, stage it (r19-verbatim protocol).
        if (tid < HDIM) {
            if (t == 0) {
                h_lds[tid] = 0.0f;
            } else {
                const u32 tag = (u32)t;
                const u64* hsD = hpD + (size_t)(t & 1) * HDIM + tid;
                const u64* hsL = hpL + (size_t)(t & 1) * HDIM + tid;
                u64 v = 0;
                bool got = false;
                if (t > WARM && !fellback) {
                    int sp = 0;
                    do {
                        v = load_b64_sc0(hsL);
                    } while ((u32)(v >> 32) != tag && ++sp < LSPIN);
                    if ((u32)(v >> 32) == tag) got = true;
                    else fellback = 1;          // sticky; never retry local
                }
                if (!got) {
                    v = __hip_atomic_load(hsD, __ATOMIC_RELAXED,
                                          __HIP_MEMORY_SCOPE_AGENT);
                    int sp = 0;
                    while (!dead && (u32)(v >> 32) != tag) {
                        if (++sp >= SPIN_MAX) { dead = 1; sdead = 1; break; }
                        v = __hip_atomic_load(hsD, __ATOMIC_RELAXED,
                                              __HIP_MEMORY_SCOPE_AGENT);
                    }
                }
                h_lds[tid] = __uint_as_float((u32)v);
            }
        }
        // post-C: issue t+1 prefetches (drain lands in D, covered).
        if (t + 1 < T_STEPS) {
            if (tid < HDIM) xr = x[(size_t)(t + 1) * HDIM + tid];
            if (epub || dpub)
                lkn = (t + 1 < T_STEPS - 1)
                    ? likes[(size_t)(t + 1) * HDIM + b * 16 + i16] : 0.0f;
        }
        bar_lds();   // #1: h_lds ready (DS drain only; VMEM stays in flight)

        // ---- D: h-dot + reduce + activation; stage x_lds(t+1) late.
        {
            const float4* h4 = (const float4*)h_lds;
            const float4 v0 = h4[lane];
            const float4 v1 = h4[64 + lane];
            a0 = fmaf(Wh[0], v0.x, a0); a0 = fmaf(Wh[1], v0.y, a0);
            a0 = fmaf(Wh[2], v0.z, a0); a0 = fmaf(Wh[3], v0.w, a0);
            a0 = fmaf(Wh[4], v1.x, a0); a0 = fmaf(Wh[5], v1.y, a0);
            a0 = fmaf(Wh[6], v1.z, a0); a0 = fmaf(Wh[7], v1.w, a0);
            a1 = fmaf(Wh[8], v0.x, a1); a1 = fmaf(Wh[9], v0.y, a1);
            a1 = fmaf(Wh[10], v0.z, a1); a1 = fmaf(Wh[11], v0.w, a1);
            a1 = fmaf(Wh[12], v1.x, a1); a1 = fmaf(Wh[13], v1.y, a1);
            a1 = fmaf(Wh[14], v1.z, a1); a1 = fmaf(Wh[15], v1.w, a1);
            a2 = fmaf(Wh[16], v0.x, a2); a2 = fmaf(Wh[17], v0.y, a2);
            a2 = fmaf(Wh[18], v0.z, a2); a2 = fmaf(Wh[19], v0.w, a2);
            a2 = fmaf(Wh[20], v1.x, a2); a2 = fmaf(Wh[21], v1.y, a2);
            a2 = fmaf(Wh[22], v1.z, a2); a2 = fmaf(Wh[23], v1.w, a2);
            a3 = fmaf(Wh[24], v0.x, a3); a3 = fmaf(Wh[25], v0.y, a3);
            a3 = fmaf(Wh[26], v0.z, a3); a3 = fmaf(Wh[27], v0.w, a3);
            a3 = fmaf(Wh[28], v1.x, a3); a3 = fmaf(Wh[29], v1.y, a3);
            a3 = fmaf(Wh[30], v1.z, a3); a3 = fmaf(Wh[31], v1.w, a3);
        }

        // full-wave reduce: DPP to 32-groups, shfl_xor(32) across halves.
        dpp_reduce4(a0, a1, a2, a3);
        a0 += __shfl_xor(a0, 32);
        a1 += __shfl_xor(a1, 32);
        a2 += __shfl_xor(a2, 32);
        a3 += __shfl_xor(a3, 32);

        if (tid < HDIM) x_lds[tid] = xr;   // stage x[t+1] (reads retired #1)

        if (lane == 16) {   // collector: full 64-sums valid here
            gate_lds[he]      = fast_sigmoid(a0 + bs0);   // i
            gate_lds[16 + he] = fast_sigmoid(a1 + bs1);   // f
            gate_lds[32 + he] = fast_tanh   (a2 + bs2);   // g
            gate_lds[48 + he] = fast_sigmoid(a3 + bs3);   // o
        }
        bar_lds();   // #2: gates + x_lds(t+1) visible (DS drain only)

        // ---- E (wave0: hpL+out) / E' (wave8: hpD, never drained by polls).
        if (epub || dpub) {
            const float gi = gate_lds[i16];
            const float gf = gate_lds[16 + i16];
            const float gg = gate_lds[32 + i16];
            const float go = gate_lds[48 + i16];
            const float cn = fmaf(gf, creg, gi * gg);
            creg = cn;
            const float hn = fmaf(go, fast_tanh(cn), lkc);
            const u64 pkt = ((u64)(u32)(t + 1) << 32) | (u64)__float_as_uint(hn);
            const size_t off = (size_t)((t + 1) & 1) * HDIM + b * 16 + i16;
            if (epub) {
                store_b64_l2(hpL + off, pkt);       // XCD L2 copy (fast path)
                if (t == T_STEPS - 1)
                    out[b * 16 + i16] = sdead ? (float)(400 + b) : hn;
            } else {
                __hip_atomic_store(hpD + off, pkt, __ATOMIC_RELAXED,
                                   __HIP_MEMORY_SCOPE_AGENT);   // MALL copy
            }
            lkc = lkn;
        }
        // All other waves proceed straight to B(t+1).
    }
}

// ---------------------------------------------------------------------------
extern "C" void kernel_launch(void* const* d_in, const int* in_sizes, int n_in,
                              void* d_out, int out_size, void* d_ws, size_t ws_size,
                              hipStream_t stream) {
    float* out = (float*)d_out;
    u64* hp    = (u64*)d_ws;                          // 16 KB dual packet dbuf
    u32* probe = (u32*)((char*)d_ws + 16384);         // probe gate flag

    const int SX = 4194304, SL = 4193792, SW = 1048576, SB = 2048;

    auto match6 = [&](int a0, int a1, int a2, int a3, int a4, int a5) {
        return n_in == 6 && in_sizes[0] == a0 && in_sizes[1] == a1 &&
               in_sizes[2] == a2 && in_sizes[3] == a3 && in_sizes[4] == a4 &&
               in_sizes[5] == a5;
    };

    // Mapping verified by r9 PASS: dict order.
    int ix, il, iwih, iwhh, ibi, ibh;
    if (match6(SX, SL, SW, SW, SB, SB)) {
        ix = 0; il = 1; iwih = 2; iwhh = 3; ibi = 4; ibh = 5;
    } else if (match6(SB, SB, SL, SW, SW, SX)) {
        ibh = 0; ibi = 1; il = 2; iwhh = 3; iwih = 4; ix = 5;
    } else if (match6(SB, SB, SW, SW, SL, SX)) {
        ibh = 0; ibi = 1; iwhh = 2; iwih = 3; il = 4; ix = 5;
    } else {
        const float v = 4.0e6f + (float)(n_in == 6 ? in_sizes[0] : 100000 * n_in);
        hipLaunchKernelGGL(diag_sizes_r22, dim3(1), dim3(512), 0, stream, v, out);
        return;
    }

    const float* x   = (const float*)d_in[ix];
    const float* lk  = (const float*)d_in[il];
    const float* wih = (const float*)d_in[iwih];
    const float* whh = (const float*)d_in[iwhh];
    const float* bih = (const float*)d_in[ibi];
    const float* bhh = (const float*)d_in[ibh];

    // Zero packets + probe each launch (capture-legal).
    hipMemsetAsync(d_ws, 0, 32768, stream);

    hipLaunchKernelGGL(probe_gate_r22, dim3(1), dim3(64), 0, stream, wih, x, probe);
    hipLaunchKernelGGL(lstm_rec_r22, dim3(NBLK_HW), dim3(1024), 0, stream,
                       x, lk, wih, whh, bih, bhh, (const u32*)probe, hp, out);
}

// Round 12
// 11825.224 us; speedup vs baseline: 1.4633x; 1.4633x over previous
//
#include <hip/hip_runtime.h>
#include <hip/hip_bf16.h>
#include <math.h>

typedef unsigned long long u64;
typedef unsigned int u32;

#define T_STEPS 8192
#define HDIM    512
#define NBLK_HW 256          // launched blocks; members are b%8==0 (XCD 0)
#define SPIN_MAX (1 << 20)   // device-path spin bound
#define LSPIN    2048        // local-path spin budget before sticky fallback
#define WARM     8           // device-path warmup steps

#if __has_builtin(__builtin_amdgcn_rcpf)
#define DEV_RCP(x) __builtin_amdgcn_rcpf(x)
#else
#define DEV_RCP(x) (1.0f / (x))
#endif
#if __has_builtin(__builtin_amdgcn_exp2f)
#define DEV_EXP2(x) __builtin_amdgcn_exp2f(x)
#else
#define DEV_EXP2(x) exp2f(x)
#endif

__device__ __forceinline__ float fast_sigmoid(float x) {
    float e = DEV_EXP2(-1.4426950408889634f * x);
    return DEV_RCP(1.0f + e);
}
__device__ __forceinline__ float fast_tanh(float x) {
    x = fminf(20.0f, fmaxf(-20.0f, x));
    float e = DEV_EXP2(-2.8853900817779268f * x);  // e^{-2x}
    return (1.0f - e) * DEV_RCP(1.0f + e);
}

// r23: shrink live-W instead of fighting the allocator. r20/r21/r22 all
// spilled (VGPR 92/56/56, FETCH +10MB scratch) on any mapping needing >32
// live W floats outside r17's exact pattern; launch_bounds had ZERO effect
// (r22 == r21 codegen). Fix: precompute XG = x @ Wih^T (r13's GEMM --
// PASSED end-to-end, layout xg[t][hb*4+g] verified) -> Wx gone. r20's
// 4-row-reuse mapping then needs only Wh[64]+4 accs ~ 90 VGPR (allocator
// demonstrably holds 124). In-loop LDS: 4 ds_read_b128/thread/step (8x
// less than r17). Reduce: r20-verified DPP ladder; collectors
// ((lane&31)==16, he=tid>>5) add bias + ONE float4 of xg (all 4 gates) and
// activate -> gate_lds. Publisher: 9th wave (tid 512-575, lanes<16)
// replicates E' deterministically (r21/r22-verified, absmax 0) and stores
// hpD EVERY step -- it never polls, so its MALL store is never vmcnt-
// drained; no pktreg deferral, no warm special-case. wave0 lanes<16 store
// hpL + out. Consumer protocol verbatim r19 (sc0 local after WARM, sticky
// fallback, SPIN_MAX + sdead).
// Step: C poll(tid<512)->h_lds | post-C prefetch xg4/lk(t+1) | #1(lds) |
// D h-dot + DPP reduce + collector act->gate_lds | #2(lds) | E/E'.
// Hazards: h_lds W(C,t) vs R(D,t): #1(t); R(D,t) vs W(C,t+1): #2(t).
// gate_lds W(D,t) vs R(E/E',t): #2(t); R(E/E',t) vs W(D,t+1): #1(t+1)
// (waves 0 and 8 run E/E' before reaching #1(t+1); reads retire at own
// lgkmcnt in bar_lds). Packet WAR: r9-verified transitive argument.
// ws_size >= 64MB+64KB verified empirically in r13 (GEMM path ran+passed).

__global__ void probe_gate_r23(const float* __restrict__ wih,
                               const float* __restrict__ x, u32* flag) {
    const int lane = threadIdx.x & 63;
    const u32 wi = ((u32)lane * 16381u) & (1048576u - 1u);
    const u32 xi = ((u32)lane * 65521u) % 4194304u;
    const float wv = wih[wi];
    const float xv = x[xi];
    const bool wok  = (fabsf(wv) <= 0.04425f);            // NaN -> false
    const bool xbig = (fabsf(xv) > 0.5f) && (fabsf(xv) < 100.0f);
    const u64 wm = __ballot(wok);
    const u64 xm = __ballot(xbig);
    if (lane == 0) {
        u32 f = 1u;
        if (__popcll(wm) < 64) f = 2u;
        else if (__popcll(xm) < 8) f = 3u;
        __hip_atomic_store(flag, f, __ATOMIC_RELAXED, __HIP_MEMORY_SCOPE_AGENT);
    }
}

__global__ void diag_sizes_r23(float v, float* out) {
    const int tid = threadIdx.x;
    out[tid] = (tid == 0) ? v : 0.0f;
}

// sc0 load: bypass L1, served by the (XCD-shared) L2. 8B single transaction.
__device__ __forceinline__ u64 load_b64_sc0(const u64* p) {
    u64 r;
    asm volatile("global_load_dwordx2 %0, %1, off sc0\n\t"
                 "s_waitcnt vmcnt(0)"
                 : "=v"(r) : "v"(p) : "memory");
    return r;
}
// plain store: lands in this XCD's L2.
__device__ __forceinline__ void store_b64_l2(u64* p, u64 v) {
    asm volatile("global_store_dwordx2 %0, %1, off"
                 :: "v"(p), "v"(v) : "memory");
}

// LDS-only barrier: drains DS ops, leaves VMEM in flight (no vmcnt drain).
__device__ __forceinline__ void bar_lds() {
    __builtin_amdgcn_sched_barrier(0);
    asm volatile("s_waitcnt lgkmcnt(0)" ::: "memory");
    __builtin_amdgcn_s_barrier();
    __builtin_amdgcn_sched_barrier(0);
}

// DPP add: a += dpp_perm(a). VALU-pipe cross-lane (no DS ops).
#define DPPADD(a, ctrl, rmask)                                              \
    a += __uint_as_float((u32)__builtin_amdgcn_update_dpp(                  \
            0, (int)__float_as_uint(a), (ctrl), (rmask), 0xF, true))
#define DPP_XOR1   0xB1   // quad_perm [1,0,3,2]
#define DPP_XOR2   0x4E   // quad_perm [2,3,0,1]
#define DPP_HMIRR  0x141  // row_half_mirror
#define DPP_MIRR   0x140  // row_mirror
#define DPP_BC15   0x142  // row_bcast15 (row_mask 0xA)

// 32-lane-group sum of 4 accs; sums valid in lanes 16-31 / 48-63.
// (verified r20/r21/r22, absmax 0)
__device__ __forceinline__ void dpp_reduce4(float& a0, float& a1,
                                            float& a2, float& a3) {
    DPPADD(a0, DPP_XOR1, 0xF);  DPPADD(a1, DPP_XOR1, 0xF);
    DPPADD(a2, DPP_XOR1, 0xF);  DPPADD(a3, DPP_XOR1, 0xF);
    DPPADD(a0, DPP_XOR2, 0xF);  DPPADD(a1, DPP_XOR2, 0xF);
    DPPADD(a2, DPP_XOR2, 0xF);  DPPADD(a3, DPP_XOR2, 0xF);
    DPPADD(a0, DPP_HMIRR, 0xF); DPPADD(a1, DPP_HMIRR, 0xF);
    DPPADD(a2, DPP_HMIRR, 0xF); DPPADD(a3, DPP_HMIRR, 0xF);
    DPPADD(a0, DPP_MIRR, 0xF);  DPPADD(a1, DPP_MIRR, 0xF);
    DPPADD(a2, DPP_MIRR, 0xF);  DPPADD(a3, DPP_MIRR, 0xF);
    DPPADD(a0, DPP_BC15, 0xA);  DPPADD(a1, DPP_BC15, 0xA);
    DPPADD(a2, DPP_BC15, 0xA);  DPPADD(a3, DPP_BC15, 0xA);
}

// ---------------------------------------------------------------------------
// XG[t][n'] = sum_k x[t][k] * wih[row(n')][k], n' = hb*4 + g,
// row(n') = (n'&3)*512 + (n'>>2). 64x64 tile, 256 threads, 4x4 microtile.
// VERBATIM from r13 (PASSED end-to-end).
// ---------------------------------------------------------------------------
#define GT 64
#define GN 64
#define GK 16
__global__ __launch_bounds__(256) void xgemm_r23(
        const float* __restrict__ x, const float* __restrict__ wih,
        float* __restrict__ xgo) {
    __shared__ __align__(16) float As[GK][GT + 4];   // [kk][m]
    __shared__ __align__(16) float Bs[GK][GN + 4];   // [kk][n]
    const int tid = threadIdx.x;
    const int t0 = blockIdx.x * GT;
    const int n0 = blockIdx.y * GN;
    const int lm  = tid >> 2;           // 0..63 row within tile
    const int lk4 = (tid & 3) << 2;     // 0,4,8,12
    const int nA  = n0 + lm;
    const int rowB = (nA & 3) * 512 + (nA >> 2);
    const float* xp = x   + (size_t)(t0 + lm) * 512 + lk4;
    const float* wp = wih + (size_t)rowB * 512 + lk4;
    const int ty = tid >> 4, tx = tid & 15;
    float acc[4][4] = {};
    for (int k0 = 0; k0 < 512; k0 += GK) {
        const float4 av = *(const float4*)(xp + k0);
        const float4 bv = *(const float4*)(wp + k0);
        __syncthreads();   // previous inner-loop reads done
        As[lk4 + 0][lm] = av.x; As[lk4 + 1][lm] = av.y;
        As[lk4 + 2][lm] = av.z; As[lk4 + 3][lm] = av.w;
        Bs[lk4 + 0][lm] = bv.x; Bs[lk4 + 1][lm] = bv.y;
        Bs[lk4 + 2][lm] = bv.z; Bs[lk4 + 3][lm] = bv.w;
        __syncthreads();   // tiles visible
#pragma unroll
        for (int kk = 0; kk < GK; ++kk) {
            const float4 a  = *(const float4*)&As[kk][ty << 2];
            const float4 bq = *(const float4*)&Bs[kk][tx << 2];
            acc[0][0] = fmaf(a.x, bq.x, acc[0][0]);
            acc[0][1] = fmaf(a.x, bq.y, acc[0][1]);
            acc[0][2] = fmaf(a.x, bq.z, acc[0][2]);
            acc[0][3] = fmaf(a.x, bq.w, acc[0][3]);
            acc[1][0] = fmaf(a.y, bq.x, acc[1][0]);
            acc[1][1] = fmaf(a.y, bq.y, acc[1][1]);
            acc[1][2] = fmaf(a.y, bq.z, acc[1][2]);
            acc[1][3] = fmaf(a.y, bq.w, acc[1][3]);
            acc[2][0] = fmaf(a.z, bq.x, acc[2][0]);
            acc[2][1] = fmaf(a.z, bq.y, acc[2][1]);
            acc[2][2] = fmaf(a.z, bq.z, acc[2][2]);
            acc[2][3] = fmaf(a.z, bq.w, acc[2][3]);
            acc[3][0] = fmaf(a.w, bq.x, acc[3][0]);
            acc[3][1] = fmaf(a.w, bq.y, acc[3][1]);
            acc[3][2] = fmaf(a.w, bq.z, acc[3][2]);
            acc[3][3] = fmaf(a.w, bq.w, acc[3][3]);
        }
    }
#pragma unroll
    for (int i = 0; i < 4; ++i) {
        float4 o;
        o.x = acc[i][0]; o.y = acc[i][1]; o.z = acc[i][2]; o.w = acc[i][3];
        *(float4*)(xgo + (size_t)(t0 + (ty << 2) + i) * 2048 + n0 + (tx << 2)) = o;
    }
}

// ---------------------------------------------------------------------------
// Fused persistent LSTM recurrence. 256 blocks x 576 threads (9 waves);
// members b%8==0 (32, one XCD). Member b owns h[16b..16b+16).
// Waves 0-7 (tid<512): he=tid>>5 (0..15), s=tid&31, hb=b*16+he; thread
// computes all 4 gate rows of he over k in {4(s+32c)+j}. Wh[64] in VGPRs.
// Wave 8 (tid 512-575, lanes<16): replicated E' + hpD publish (never polls).
// ---------------------------------------------------------------------------
__global__ __launch_bounds__(576, 1) void lstm_rec_r23(
        const float* __restrict__ xg, const float* __restrict__ likes,
        const float* __restrict__ whh, const float* __restrict__ bih,
        const float* __restrict__ bhh, const u32* __restrict__ dflag,
        u64* hp, float* __restrict__ out) {
    const int tid = threadIdx.x;
    const int bhw = blockIdx.x;
    if (bhw & 7) return;            // non-members exit (other XCDs)
    const int b = bhw >> 3;

    const u32 f = __hip_atomic_load(dflag, __ATOMIC_RELAXED,
                                    __HIP_MEMORY_SCOPE_AGENT);
    if (f != 1u) {
        if (b == 0 && tid == 0) out[0] = (f == 2u) ? 9000.0f : 9500.0f;
        return;
    }

    const int lane = tid & 63;
    const int he   = (tid < HDIM) ? (tid >> 5) : 0;   // h element 0..15
    const int s    = tid & 31;                         // k-sub 0..31
    const int hb   = b * 16 + he;
    const bool comp = (tid < HDIM);                    // waves 0-7
    const bool coll = comp && ((lane & 31) == 16);     // 16 collectors
    const bool epub = (tid < 16);                      // wave0: hpL + out
    const bool dpub = (tid >= 512 && tid < 528);       // wave8: hpD
    const int  i16  = tid & 15;                        // publisher h-elem

    __shared__ __align__(16) float h_lds[HDIM];
    __shared__ float gate_lds[64];      // ACTIVATED gates: i,f,g,o x 16
    __shared__ int   sdead;

    u64* hpD = hp;                  // device-coherent packet dbuf (MALL path)
    u64* hpL = hp + 2 * HDIM;       // XCD-L2 packet dbuf (fast path)

    // Wh[g*16 + c*4 + j] = whh[(g*512+hb)*512 + 4*(s+32c)+j]  (r20 layout)
    float Wh[64];
    if (comp) {
#pragma unroll
        for (int g = 0; g < 4; ++g) {
            const float* wr = whh + (size_t)((g << 9) + hb) * 512 + (s << 2);
#pragma unroll
            for (int c = 0; c < 4; ++c) {
                const float4 v = *(const float4*)(wr + (c << 7));
                Wh[(g << 4) + (c << 2) + 0] = v.x;
                Wh[(g << 4) + (c << 2) + 1] = v.y;
                Wh[(g << 4) + (c << 2) + 2] = v.z;
                Wh[(g << 4) + (c << 2) + 3] = v.w;
            }
        }
    }
    const float bs0 = bih[hb]        + bhh[hb];
    const float bs1 = bih[512 + hb]  + bhh[512 + hb];
    const float bs2 = bih[1024 + hb] + bhh[1024 + hb];
    const float bs3 = bih[1536 + hb] + bhh[1536 + hb];

    // prologue: xg/lk for t=0; zero sdead.
    float4 xgc; xgc.x = xgc.y = xgc.z = xgc.w = 0.0f;
    float4 xgn = xgc;
    if (coll) xgc = *(const float4*)(xg + (hb << 2));
    float lkc = 0.0f, lkn = 0.0f;
    if (epub || dpub) lkc = likes[b * 16 + i16];
    if (tid == 0) sdead = 0;
    __syncthreads();   // prologue barrier (full): sdead visible

    float creg     = 0.0f;   // replicated in wave0/wave8 publisher lanes
    int   dead     = 0;
    int   fellback = 0;      // sticky: local path timed out -> device path

    for (int t = 0; t < T_STEPS; ++t) {
        // ---- C: obtain h_t, stage it (r19-verbatim protocol; tid<512).
        if (comp) {
            if (t == 0) {
                h_lds[tid] = 0.0f;
            } else {
                const u32 tag = (u32)t;
                const u64* hsD = hpD + (size_t)(t & 1) * HDIM + tid;
                const u64* hsL = hpL + (size_t)(t & 1) * HDIM + tid;
                u64 v = 0;
                bool got = false;
                if (t > WARM && !fellback) {
                    int sp = 0;
                    do {
                        v = load_b64_sc0(hsL);
                    } while ((u32)(v >> 32) != tag && ++sp < LSPIN);
                    if ((u32)(v >> 32) == tag) got = true;
                    else fellback = 1;          // sticky; never retry local
                }
                if (!got) {
                    v = __hip_atomic_load(hsD, __ATOMIC_RELAXED,
                                          __HIP_MEMORY_SCOPE_AGENT);
                    int sp = 0;
                    while (!dead && (u32)(v >> 32) != tag) {
                        if (++sp >= SPIN_MAX) { dead = 1; sdead = 1; break; }
                        v = __hip_atomic_load(hsD, __ATOMIC_RELAXED,
                                              __HIP_MEMORY_SCOPE_AGENT);
                    }
                }
                h_lds[tid] = __uint_as_float((u32)v);
            }
        }
        // post-C: issue t+1 prefetches (retire covered by #1+D+#2+E before
        // the NEXT step's poll vmcnt(0)).
        if (t + 1 < T_STEPS) {
            if (coll)
                xgn = *(const float4*)(xg + (size_t)(t + 1) * 2048 + (hb << 2));
            if (epub || dpub)
                lkn = (t + 1 < T_STEPS - 1)
                    ? likes[(size_t)(t + 1) * HDIM + b * 16 + i16] : 0.0f;
        }
        bar_lds();   // #1: h_lds ready (DS drain only; VMEM stays in flight)

        // ---- D: h-dot (4 b128, 64 FMA) + DPP reduce + collector act.
        float a0 = 0.0f, a1 = 0.0f, a2 = 0.0f, a3 = 0.0f;
        if (comp) {
            const float4* h4 = (const float4*)h_lds;
#pragma unroll
            for (int c = 0; c < 4; ++c) {
                const float4 v = h4[s + (c << 5)];
                a0 = fmaf(Wh[(c << 2) + 0], v.x, a0);
                a0 = fmaf(Wh[(c << 2) + 1], v.y, a0);
                a0 = fmaf(Wh[(c << 2) + 2], v.z, a0);
                a0 = fmaf(Wh[(c << 2) + 3], v.w, a0);
                a1 = fmaf(Wh[16 + (c << 2) + 0], v.x, a1);
                a1 = fmaf(Wh[16 + (c << 2) + 1], v.y, a1);
                a1 = fmaf(Wh[16 + (c << 2) + 2], v.z, a1);
                a1 = fmaf(Wh[16 + (c << 2) + 3], v.w, a1);
                a2 = fmaf(Wh[32 + (c << 2) + 0], v.x, a2);
                a2 = fmaf(Wh[32 + (c << 2) + 1], v.y, a2);
                a2 = fmaf(Wh[32 + (c << 2) + 2], v.z, a2);
                a2 = fmaf(Wh[32 + (c << 2) + 3], v.w, a2);
                a3 = fmaf(Wh[48 + (c << 2) + 0], v.x, a3);
                a3 = fmaf(Wh[48 + (c << 2) + 1], v.y, a3);
                a3 = fmaf(Wh[48 + (c << 2) + 2], v.z, a3);
                a3 = fmaf(Wh[48 + (c << 2) + 3], v.w, a3);
            }
            dpp_reduce4(a0, a1, a2, a3);
            if (coll) {   // full 32-sums valid in lanes 16/48
                gate_lds[he]      = fast_sigmoid(a0 + bs0 + xgc.x);   // i
                gate_lds[16 + he] = fast_sigmoid(a1 + bs1 + xgc.y);   // f
                gate_lds[32 + he] = fast_tanh   (a2 + bs2 + xgc.z);   // g
                gate_lds[48 + he] = fast_sigmoid(a3 + bs3 + xgc.w);   // o
            }
        }
        bar_lds();   // #2: gates visible (DS drain only)

        // ---- E (wave0: hpL+out) / E' (wave8: hpD, never vmcnt-drained).
        if (epub || dpub) {
            const float gi = gate_lds[i16];
            const float gf = gate_lds[16 + i16];
            const float gg = gate_lds[32 + i16];
            const float go = gate_lds[48 + i16];
            const float cn = fmaf(gf, creg, gi * gg);
            creg = cn;
            const float hn = fmaf(go, fast_tanh(cn), lkc);
            const u64 pkt = ((u64)(u32)(t + 1) << 32) | (u64)__float_as_uint(hn);
            const size_t off = (size_t)((t + 1) & 1) * HDIM + b * 16 + i16;
            if (epub) {
                store_b64_l2(hpL + off, pkt);       // XCD L2 copy (fast path)
                if (t == T_STEPS - 1)
                    out[b * 16 + i16] = sdead ? (float)(400 + b) : hn;
            } else {
                __hip_atomic_store(hpD + off, pkt, __ATOMIC_RELAXED,
                                   __HIP_MEMORY_SCOPE_AGENT);   // MALL copy
            }
            lkc = lkn;
        }
        xgc = xgn;
        // Non-publisher waves proceed straight to C(t+1).
    }
}

// ---------------------------------------------------------------------------
extern "C" void kernel_launch(void* const* d_in, const int* in_sizes, int n_in,
                              void* d_out, int out_size, void* d_ws, size_t ws_size,
                              hipStream_t stream) {
    float* out = (float*)d_out;
    u64* hp    = (u64*)d_ws;                          // 16 KB dual packet dbuf
    u32* probe = (u32*)((char*)d_ws + 16384);         // probe gate flag
    float* xg  = (float*)((char*)d_ws + 65536);       // 64 MB precomputed XG
    const size_t need = 65536 + (size_t)T_STEPS * 2048 * sizeof(float);

    const int SX = 4194304, SL = 4193792, SW = 1048576, SB = 2048;

    auto match6 = [&](int a0, int a1, int a2, int a3, int a4, int a5) {
        return n_in == 6 && in_sizes[0] == a0 && in_sizes[1] == a1 &&
               in_sizes[2] == a2 && in_sizes[3] == a3 && in_sizes[4] == a4 &&
               in_sizes[5] == a5;
    };

    // Mapping verified by r9 PASS: dict order.
    int ix, il, iwih, iwhh, ibi, ibh;
    if (match6(SX, SL, SW, SW, SB, SB)) {
        ix = 0; il = 1; iwih = 2; iwhh = 3; ibi = 4; ibh = 5;
    } else if (match6(SB, SB, SL, SW, SW, SX)) {
        ibh = 0; ibi = 1; il = 2; iwhh = 3; iwih = 4; ix = 5;
    } else if (match6(SB, SB, SW, SW, SL, SX)) {
        ibh = 0; ibi = 1; iwhh = 2; iwih = 3; il = 4; ix = 5;
    } else {
        const float v = 4.0e6f + (float)(n_in == 6 ? in_sizes[0] : 100000 * n_in);
        hipLaunchKernelGGL(diag_sizes_r23, dim3(1), dim3(512), 0, stream, v, out);
        return;
    }

    if (ws_size < need) {   // loud failure (r13 verified ws is big enough)
        hipLaunchKernelGGL(diag_sizes_r23, dim3(1), dim3(512), 0, stream,
                           5.0e6f, out);
        return;
    }

    const float* x   = (const float*)d_in[ix];
    const float* lk  = (const float*)d_in[il];
    const float* wih = (const float*)d_in[iwih];
    const float* whh = (const float*)d_in[iwhh];
    const float* bih = (const float*)d_in[ibi];
    const float* bhh = (const float*)d_in[ibh];

    // Zero packets + probe each launch (capture-legal).
    hipMemsetAsync(d_ws, 0, 32768, stream);

    hipLaunchKernelGGL(probe_gate_r23, dim3(1), dim3(64), 0, stream, wih, x, probe);
    hipLaunchKernelGGL(xgemm_r23, dim3(T_STEPS / GT, 2048 / GN), dim3(256),
                       0, stream, x, wih, xg);
    hipLaunchKernelGGL(lstm_rec_r23, dim3(NBLK_HW), dim3(576), 0, stream,
                       xg, lk, whh, bih, bhh, (const u32*)probe, hp, out);
}